// Round 3
// baseline (1039.971 us; speedup 1.0000x reference)
//
#include <hip/hip_runtime.h>

// GCN: 3x (h = X@W; agg = CSR-gather(norm_e * h[src]) + norm_self*h + b; relu)
// then mean-pool by graph id and a 128x8 linear head.
// R1: atomic scatter -> CSR gather (no f32 atomics in hot path).
// R2: gather inner loop restructured for memory-level parallelism:
//     coalesced 32-wide index loads + shfl broadcast + 8 float4 gathers in
//     flight (was 2 -> dependent-load latency bound, VGPR=16).

#define THREADS 256

// ---------------- degree(int) / counts / dinv ----------------

__global__ __launch_bounds__(THREADS) void k_deg(const int* __restrict__ dst,
                                                 int* __restrict__ degi, int E) {
  int e = blockIdx.x * THREADS + threadIdx.x;
  if (e < E) atomicAdd(&degi[dst[e]], 1);
}

__global__ __launch_bounds__(THREADS) void k_cnt(const int* __restrict__ batch,
                                                 float* __restrict__ cnts, int N) {
  int i = blockIdx.x * THREADS + threadIdx.x;
  if (i < N) atomicAdd(&cnts[batch[i]], 1.0f);
}

__global__ __launch_bounds__(THREADS) void k_rsq(const int* __restrict__ degi,
                                                 float* __restrict__ dinv, int N) {
  int i = blockIdx.x * THREADS + threadIdx.x;
  if (i < N) dinv[i] = rsqrtf((float)degi[i] + 1.0f);
}

// ---------------- exclusive scan (3 kernels) ----------------

__global__ __launch_bounds__(THREADS) void k_scan1(const int* __restrict__ degi,
                                                   int* __restrict__ rowptr,
                                                   int* __restrict__ bsum, int N) {
  __shared__ int s[THREADS];
  int i = blockIdx.x * THREADS + threadIdx.x;
  int v = (i < N) ? degi[i] : 0;
  s[threadIdx.x] = v;
  __syncthreads();
#pragma unroll
  for (int off = 1; off < THREADS; off <<= 1) {
    int t = (threadIdx.x >= off) ? s[threadIdx.x - off] : 0;
    __syncthreads();
    s[threadIdx.x] += t;
    __syncthreads();
  }
  if (i < N) rowptr[i] = s[threadIdx.x] - v;  // exclusive
  if (threadIdx.x == THREADS - 1) bsum[blockIdx.x] = s[THREADS - 1];
}

__global__ __launch_bounds__(512) void k_scan2(int* __restrict__ bsum, int nb) {
  __shared__ int s[512];
  int v = (threadIdx.x < nb) ? bsum[threadIdx.x] : 0;
  s[threadIdx.x] = v;
  __syncthreads();
#pragma unroll
  for (int off = 1; off < 512; off <<= 1) {
    int t = (threadIdx.x >= off) ? s[threadIdx.x - off] : 0;
    __syncthreads();
    s[threadIdx.x] += t;
    __syncthreads();
  }
  if (threadIdx.x < nb) bsum[threadIdx.x] = s[threadIdx.x] - v;  // exclusive
}

__global__ __launch_bounds__(THREADS) void k_scan3(int* __restrict__ rowptr,
                                                   const int* __restrict__ bsum,
                                                   int N, int E) {
  int i = blockIdx.x * THREADS + threadIdx.x;
  if (i < N) rowptr[i] += bsum[blockIdx.x];
  if (i == 0) rowptr[N] = E;
}

// ---------------- CSR placement: csr_src/csr_w by dst ----------------

__global__ __launch_bounds__(THREADS) void k_csr(const int* __restrict__ src,
                                                 const int* __restrict__ dst,
                                                 const int* __restrict__ rowptr,
                                                 int* __restrict__ cursor,
                                                 const float* __restrict__ dinv,
                                                 int* __restrict__ csr_src,
                                                 float* __restrict__ csr_w, int E) {
  int e = blockIdx.x * THREADS + threadIdx.x;
  if (e >= E) return;
  int s = src[e];
  int d = dst[e];
  int pos = atomicAdd(&cursor[d], 1);
  int idx = rowptr[d] + pos;
  csr_src[idx] = s;
  csr_w[idx] = dinv[s] * dinv[d];
}

// ---------------- GEMM: H[M,128] = X[M,128] @ W[128,128] ----------------

__global__ __launch_bounds__(THREADS) void k_gemm128(const float* __restrict__ X,
                                                     const float* __restrict__ W,
                                                     float* __restrict__ H, int M) {
  __shared__ float4 sW[128 * 32];  // [k][colgroup] : W[k][c0..c0+3]
  const int t = threadIdx.x;
#pragma unroll
  for (int i = 0; i < 16; ++i) sW[t + i * 256] = ((const float4*)W)[t + i * 256];
  __syncthreads();

  const int tx = t & 31;
  const int ty = t >> 5;
  const int r0 = blockIdx.x * 64 + ty * 8;

  const float* xp[8];
#pragma unroll
  for (int i = 0; i < 8; ++i) {
    int r = r0 + i;
    if (r >= M) r = M - 1;
    xp[i] = X + (size_t)r * 128;
  }

  float4 acc[8];
#pragma unroll
  for (int i = 0; i < 8; ++i) acc[i] = make_float4(0.f, 0.f, 0.f, 0.f);

#pragma unroll 2
  for (int k = 0; k < 128; k += 4) {
    float4 xv[8];
#pragma unroll
    for (int i = 0; i < 8; ++i) xv[i] = *(const float4*)(xp[i] + k);
#pragma unroll
    for (int kk = 0; kk < 4; ++kk) {
      float4 w = sW[(k + kk) * 32 + tx];
#pragma unroll
      for (int i = 0; i < 8; ++i) {
        float xs = (kk == 0) ? xv[i].x : (kk == 1) ? xv[i].y : (kk == 2) ? xv[i].z : xv[i].w;
        acc[i].x = fmaf(xs, w.x, acc[i].x);
        acc[i].y = fmaf(xs, w.y, acc[i].y);
        acc[i].z = fmaf(xs, w.z, acc[i].z);
        acc[i].w = fmaf(xs, w.w, acc[i].w);
      }
    }
  }

#pragma unroll
  for (int i = 0; i < 8; ++i) {
    int r = r0 + i;
    if (r < M) *(float4*)(H + (size_t)r * 128 + tx * 4) = acc[i];
  }
}

// ---------------- gather: B[i] = sum_in csr_w*H[src] + dinv_i^2*H[i] + bias ----------------
// 32 lanes per dst node, float4 per lane. Coalesced index loads + shfl
// broadcast; 8 gathers in flight. Ragged tail padded with (s=0, w=0) — the
// pad loads hit L1 (row 0). Optional relu; optional fused pool.

__global__ __launch_bounds__(THREADS) void k_gather(const float* __restrict__ H,
                                                    const int* __restrict__ rowptr,
                                                    const int* __restrict__ csr_src,
                                                    const float* __restrict__ csr_w,
                                                    const float* __restrict__ dinv,
                                                    const float* __restrict__ bias,
                                                    float* __restrict__ Bout, int N,
                                                    int relu,
                                                    const int* __restrict__ batch,
                                                    float* __restrict__ pooled) {
  int gid = blockIdx.x * THREADS + threadIdx.x;
  int i = gid >> 5;
  int lane = gid & 31;
  if (i >= N) return;
  int beg = rowptr[i];
  int end = rowptr[i + 1];

  float4 acc = make_float4(0.f, 0.f, 0.f, 0.f);

  for (int base = beg; base < end; base += 32) {
    int idx = base + lane;
    bool ok = idx < end;
    int s = ok ? csr_src[idx] : 0;      // coalesced 32-wide load
    float w = ok ? csr_w[idx] : 0.f;
    int cnt = end - base;
    if (cnt > 32) cnt = 32;
    int cnt8 = (cnt + 7) & ~7;          // round up; pads have w==0

    for (int j = 0; j < cnt8; j += 8) {
      int ss[8];
      float ww[8];
#pragma unroll
      for (int u = 0; u < 8; ++u) {
        ss[u] = __shfl(s, j + u, 32);
        ww[u] = __shfl(w, j + u, 32);
      }
      float4 h[8];
#pragma unroll
      for (int u = 0; u < 8; ++u)
        h[u] = *(const float4*)(H + (size_t)ss[u] * 128 + lane * 4);
#pragma unroll
      for (int u = 0; u < 8; ++u) {
        acc.x = fmaf(ww[u], h[u].x, acc.x);
        acc.y = fmaf(ww[u], h[u].y, acc.y);
        acc.z = fmaf(ww[u], h[u].z, acc.z);
        acc.w = fmaf(ww[u], h[u].w, acc.w);
      }
    }
  }

  float di = dinv[i];
  float ns = di * di;
  float4 hs = *(const float4*)(H + (size_t)i * 128 + lane * 4);
  float4 bb = *(const float4*)(bias + lane * 4);
  float4 v;
  v.x = fmaf(hs.x, ns, acc.x) + bb.x;
  v.y = fmaf(hs.y, ns, acc.y) + bb.y;
  v.z = fmaf(hs.z, ns, acc.z) + bb.z;
  v.w = fmaf(hs.w, ns, acc.w) + bb.w;
  if (relu) {
    v.x = fmaxf(v.x, 0.f);
    v.y = fmaxf(v.y, 0.f);
    v.z = fmaxf(v.z, 0.f);
    v.w = fmaxf(v.w, 0.f);
  }
  *(float4*)(Bout + (size_t)i * 128 + lane * 4) = v;

  if (pooled) {
    int g = batch[i];
    float* o = pooled + (size_t)g * 128 + lane * 4;
    atomicAdd(o + 0, v.x);
    atomicAdd(o + 1, v.y);
    atomicAdd(o + 2, v.z);
    atomicAdd(o + 3, v.w);
  }
}

// ---------------- head ----------------

__global__ __launch_bounds__(THREADS) void k_head(const float* __restrict__ pooled,
                                                  const float* __restrict__ cnts,
                                                  const float* __restrict__ Wl,
                                                  const float* __restrict__ bl,
                                                  float* __restrict__ out, int G) {
  int gid = blockIdx.x * THREADS + threadIdx.x;
  int g = gid >> 3;
  int o = gid & 7;
  if (g >= G) return;
  float acc = 0.f;
#pragma unroll 8
  for (int k = 0; k < 128; ++k) acc = fmaf(pooled[(size_t)g * 128 + k], Wl[k * 8 + o], acc);
  out[g * 8 + o] = acc / fmaxf(cnts[g], 1.0f) + bl[o];
}

// ---------------- launch ----------------

extern "C" void kernel_launch(void* const* d_in, const int* in_sizes, int n_in,
                              void* d_out, int out_size, void* d_ws, size_t ws_size,
                              hipStream_t stream) {
  const float* x     = (const float*)d_in[0];
  const int*   ei    = (const int*)d_in[1];
  const int*   batch = (const int*)d_in[3];
  const float* W1 = (const float*)d_in[4];
  const float* b1 = (const float*)d_in[5];
  const float* W2 = (const float*)d_in[6];
  const float* b2 = (const float*)d_in[7];
  const float* W3 = (const float*)d_in[8];
  const float* b3 = (const float*)d_in[9];
  const float* Wl = (const float*)d_in[10];
  const float* bl = (const float*)d_in[11];
  float* out = (float*)d_out;

  const int N = in_sizes[0] / 128;
  const int E = in_sizes[1] / 2;
  const int G = out_size / 8;
  const int* srcp = ei;
  const int* dstp = ei + E;

  char* ws = (char*)d_ws;
  float* A = (float*)ws;                       // [N,128] h buffer
  float* B = A + (size_t)N * 128;              // [N,128] agg/activation buffer
  // zeroed region: degi, cursor, cnts, pooled (contiguous)
  int*   degi   = (int*)(B + (size_t)N * 128); // N
  int*   cursor = degi + N;                    // N
  float* cnts   = (float*)(cursor + N);        // G
  float* pooled = cnts + G;                    // G*128
  // non-zeroed scratch
  float* dinv    = pooled + (size_t)G * 128;   // N
  int*   rowptr  = (int*)(dinv + N);           // N+1
  int*   bsum    = rowptr + N + 1;             // scan partials (<=2048)
  int*   csr_src = bsum + 2048;                // E
  float* csr_w   = (float*)(csr_src + E);      // E

  const size_t zero_bytes = ((size_t)2 * N + G + (size_t)G * 128) * sizeof(float);
  hipMemsetAsync(degi, 0, zero_bytes, stream);

  const int nbE = (E + THREADS - 1) / THREADS;
  const int nbN = (N + THREADS - 1) / THREADS;

  // ---- CSR build (once per call, reused by all 3 layers) ----
  k_deg<<<nbE, THREADS, 0, stream>>>(dstp, degi, E);
  k_cnt<<<nbN, THREADS, 0, stream>>>(batch, cnts, N);
  k_rsq<<<nbN, THREADS, 0, stream>>>(degi, dinv, N);
  k_scan1<<<nbN, THREADS, 0, stream>>>(degi, rowptr, bsum, N);
  k_scan2<<<1, 512, 0, stream>>>(bsum, nbN);
  k_scan3<<<nbN, THREADS, 0, stream>>>(rowptr, bsum, N, E);
  k_csr<<<nbE, THREADS, 0, stream>>>(srcp, dstp, rowptr, cursor, dinv, csr_src, csr_w, E);

  const int gemm_blocks = (N + 63) / 64;
  const int gat_blocks = (int)(((long long)N * 32 + THREADS - 1) / THREADS);

  // ---- layer 1 ----
  k_gemm128<<<gemm_blocks, THREADS, 0, stream>>>(x, W1, A, N);
  k_gather<<<gat_blocks, THREADS, 0, stream>>>(A, rowptr, csr_src, csr_w, dinv, b1, B, N, 1,
                                               nullptr, nullptr);
  // ---- layer 2 ----
  k_gemm128<<<gemm_blocks, THREADS, 0, stream>>>(B, W2, A, N);
  k_gather<<<gat_blocks, THREADS, 0, stream>>>(A, rowptr, csr_src, csr_w, dinv, b2, B, N, 1,
                                               nullptr, nullptr);
  // ---- layer 3 (no relu, fused mean-pool accumulation) ----
  k_gemm128<<<gemm_blocks, THREADS, 0, stream>>>(B, W3, A, N);
  k_gather<<<gat_blocks, THREADS, 0, stream>>>(A, rowptr, csr_src, csr_w, dinv, b3, B, N, 0,
                                               batch, pooled);

  // ---- head ----
  k_head<<<(G * 8 + THREADS - 1) / THREADS, THREADS, 0, stream>>>(pooled, cnts, Wl, bl, out, G);
}

// Round 5
// 882.195 us; speedup vs baseline: 1.1788x; 1.1788x over previous
//
#include <hip/hip_runtime.h>
#include <hip/hip_fp16.h>

// GCN: 3x (h = X@W; agg = CSR-gather(norm_e * h[src]) + norm_self*h + b; relu)
// then mean-pool by graph id and a 128x8 linear head.
// R1: atomic scatter -> CSR gather (no f32 atomics in hot path).
// R2 (reverted): MLP-8 shfl gather regressed -> gather is L2-miss BW-bound,
//     not latency-bound (404 MB fetch vs 51 MB H).
// R3: GEMM outputs fp16 H16 (25.6 MB); gather payload halves (256 B/edge).
//     Aggregation math, B, GEMM accum all stay fp32.
// R4: resubmit of R3 (container infra failure, no measurement).

#define THREADS 256

// ---------------- degree(int) / counts / dinv ----------------

__global__ __launch_bounds__(THREADS) void k_deg(const int* __restrict__ dst,
                                                 int* __restrict__ degi, int E) {
  int e = blockIdx.x * THREADS + threadIdx.x;
  if (e < E) atomicAdd(&degi[dst[e]], 1);
}

__global__ __launch_bounds__(THREADS) void k_cnt(const int* __restrict__ batch,
                                                 float* __restrict__ cnts, int N) {
  int i = blockIdx.x * THREADS + threadIdx.x;
  if (i < N) atomicAdd(&cnts[batch[i]], 1.0f);
}

__global__ __launch_bounds__(THREADS) void k_rsq(const int* __restrict__ degi,
                                                 float* __restrict__ dinv, int N) {
  int i = blockIdx.x * THREADS + threadIdx.x;
  if (i < N) dinv[i] = rsqrtf((float)degi[i] + 1.0f);
}

// ---------------- exclusive scan (3 kernels) ----------------

__global__ __launch_bounds__(THREADS) void k_scan1(const int* __restrict__ degi,
                                                   int* __restrict__ rowptr,
                                                   int* __restrict__ bsum, int N) {
  __shared__ int s[THREADS];
  int i = blockIdx.x * THREADS + threadIdx.x;
  int v = (i < N) ? degi[i] : 0;
  s[threadIdx.x] = v;
  __syncthreads();
#pragma unroll
  for (int off = 1; off < THREADS; off <<= 1) {
    int t = (threadIdx.x >= off) ? s[threadIdx.x - off] : 0;
    __syncthreads();
    s[threadIdx.x] += t;
    __syncthreads();
  }
  if (i < N) rowptr[i] = s[threadIdx.x] - v;  // exclusive
  if (threadIdx.x == THREADS - 1) bsum[blockIdx.x] = s[THREADS - 1];
}

__global__ __launch_bounds__(512) void k_scan2(int* __restrict__ bsum, int nb) {
  __shared__ int s[512];
  int v = (threadIdx.x < nb) ? bsum[threadIdx.x] : 0;
  s[threadIdx.x] = v;
  __syncthreads();
#pragma unroll
  for (int off = 1; off < 512; off <<= 1) {
    int t = (threadIdx.x >= off) ? s[threadIdx.x - off] : 0;
    __syncthreads();
    s[threadIdx.x] += t;
    __syncthreads();
  }
  if (threadIdx.x < nb) bsum[threadIdx.x] = s[threadIdx.x] - v;  // exclusive
}

__global__ __launch_bounds__(THREADS) void k_scan3(int* __restrict__ rowptr,
                                                   const int* __restrict__ bsum,
                                                   int N, int E) {
  int i = blockIdx.x * THREADS + threadIdx.x;
  if (i < N) rowptr[i] += bsum[blockIdx.x];
  if (i == 0) rowptr[N] = E;
}

// ---------------- CSR placement: csr_src/csr_w by dst ----------------

__global__ __launch_bounds__(THREADS) void k_csr(const int* __restrict__ src,
                                                 const int* __restrict__ dst,
                                                 const int* __restrict__ rowptr,
                                                 int* __restrict__ cursor,
                                                 const float* __restrict__ dinv,
                                                 int* __restrict__ csr_src,
                                                 float* __restrict__ csr_w, int E) {
  int e = blockIdx.x * THREADS + threadIdx.x;
  if (e >= E) return;
  int s = src[e];
  int d = dst[e];
  int pos = atomicAdd(&cursor[d], 1);
  int idx = rowptr[d] + pos;
  csr_src[idx] = s;
  csr_w[idx] = dinv[s] * dinv[d];
}

// ---------------- GEMM: H16[M,128] = fp16(X[M,128] @ W[128,128]) ----------------

__global__ __launch_bounds__(THREADS) void k_gemm128(const float* __restrict__ X,
                                                     const float* __restrict__ W,
                                                     __half* __restrict__ H16, int M) {
  __shared__ float4 sW[128 * 32];  // [k][colgroup] : W[k][c0..c0+3]
  const int t = threadIdx.x;
#pragma unroll
  for (int i = 0; i < 16; ++i) sW[t + i * 256] = ((const float4*)W)[t + i * 256];
  __syncthreads();

  const int tx = t & 31;
  const int ty = t >> 5;
  const int r0 = blockIdx.x * 64 + ty * 8;

  const float* xp[8];
#pragma unroll
  for (int i = 0; i < 8; ++i) {
    int r = r0 + i;
    if (r >= M) r = M - 1;
    xp[i] = X + (size_t)r * 128;
  }

  float4 acc[8];
#pragma unroll
  for (int i = 0; i < 8; ++i) acc[i] = make_float4(0.f, 0.f, 0.f, 0.f);

#pragma unroll 2
  for (int k = 0; k < 128; k += 4) {
    float4 xv[8];
#pragma unroll
    for (int i = 0; i < 8; ++i) xv[i] = *(const float4*)(xp[i] + k);
#pragma unroll
    for (int kk = 0; kk < 4; ++kk) {
      float4 w = sW[(k + kk) * 32 + tx];
#pragma unroll
      for (int i = 0; i < 8; ++i) {
        float xs = (kk == 0) ? xv[i].x : (kk == 1) ? xv[i].y : (kk == 2) ? xv[i].z : xv[i].w;
        acc[i].x = fmaf(xs, w.x, acc[i].x);
        acc[i].y = fmaf(xs, w.y, acc[i].y);
        acc[i].z = fmaf(xs, w.z, acc[i].z);
        acc[i].w = fmaf(xs, w.w, acc[i].w);
      }
    }
  }

#pragma unroll
  for (int i = 0; i < 8; ++i) {
    int r = r0 + i;
    if (r < M) {
      __half2 p[2];
      p[0] = __floats2half2_rn(acc[i].x, acc[i].y);
      p[1] = __floats2half2_rn(acc[i].z, acc[i].w);
      *(float2*)(H16 + (size_t)r * 128 + tx * 4) = *(float2*)p;
    }
  }
}

// ---------------- fp16 row-fragment load: 4 halves (8 B) -> float4 ----------------

__device__ inline float4 ld_h4(const __half* __restrict__ p) {
  float2 raw = *(const float2*)p;
  const __half2* h = (const __half2*)&raw;
  float2 a = __half22float2(h[0]);
  float2 b = __half22float2(h[1]);
  return make_float4(a.x, a.y, b.x, b.y);
}

// ---------------- gather: B[i] = sum_in csr_w*H16[src] + dinv_i^2*H16[i] + bias ----------------
// 32 lanes per dst node, 4 halves (8 B) per lane (256 B/edge payload).

__global__ __launch_bounds__(THREADS) void k_gather(const __half* __restrict__ H16,
                                                    const int* __restrict__ rowptr,
                                                    const int* __restrict__ csr_src,
                                                    const float* __restrict__ csr_w,
                                                    const float* __restrict__ dinv,
                                                    const float* __restrict__ bias,
                                                    float* __restrict__ Bout, int N,
                                                    int relu,
                                                    const int* __restrict__ batch,
                                                    float* __restrict__ pooled) {
  int gid = blockIdx.x * THREADS + threadIdx.x;
  int i = gid >> 5;
  int lane = gid & 31;
  if (i >= N) return;
  int beg = rowptr[i];
  int end = rowptr[i + 1];

  float4 acc = make_float4(0.f, 0.f, 0.f, 0.f);
  int k = beg;
  for (; k + 3 < end; k += 4) {
    int s0 = csr_src[k],     s1 = csr_src[k + 1];
    int s2 = csr_src[k + 2], s3 = csr_src[k + 3];
    float w0 = csr_w[k],     w1 = csr_w[k + 1];
    float w2 = csr_w[k + 2], w3 = csr_w[k + 3];
    float4 h0 = ld_h4(H16 + (size_t)s0 * 128 + lane * 4);
    float4 h1 = ld_h4(H16 + (size_t)s1 * 128 + lane * 4);
    float4 h2 = ld_h4(H16 + (size_t)s2 * 128 + lane * 4);
    float4 h3 = ld_h4(H16 + (size_t)s3 * 128 + lane * 4);
    acc.x = fmaf(w0, h0.x, acc.x); acc.y = fmaf(w0, h0.y, acc.y);
    acc.z = fmaf(w0, h0.z, acc.z); acc.w = fmaf(w0, h0.w, acc.w);
    acc.x = fmaf(w1, h1.x, acc.x); acc.y = fmaf(w1, h1.y, acc.y);
    acc.z = fmaf(w1, h1.z, acc.z); acc.w = fmaf(w1, h1.w, acc.w);
    acc.x = fmaf(w2, h2.x, acc.x); acc.y = fmaf(w2, h2.y, acc.y);
    acc.z = fmaf(w2, h2.z, acc.z); acc.w = fmaf(w2, h2.w, acc.w);
    acc.x = fmaf(w3, h3.x, acc.x); acc.y = fmaf(w3, h3.y, acc.y);
    acc.z = fmaf(w3, h3.z, acc.z); acc.w = fmaf(w3, h3.w, acc.w);
  }
  for (; k < end; ++k) {
    int s0 = csr_src[k];
    float w0 = csr_w[k];
    float4 h0 = ld_h4(H16 + (size_t)s0 * 128 + lane * 4);
    acc.x = fmaf(w0, h0.x, acc.x); acc.y = fmaf(w0, h0.y, acc.y);
    acc.z = fmaf(w0, h0.z, acc.z); acc.w = fmaf(w0, h0.w, acc.w);
  }

  float di = dinv[i];
  float ns = di * di;
  float4 hs = ld_h4(H16 + (size_t)i * 128 + lane * 4);
  float4 bb = *(const float4*)(bias + lane * 4);
  float4 v;
  v.x = fmaf(hs.x, ns, acc.x) + bb.x;
  v.y = fmaf(hs.y, ns, acc.y) + bb.y;
  v.z = fmaf(hs.z, ns, acc.z) + bb.z;
  v.w = fmaf(hs.w, ns, acc.w) + bb.w;
  if (relu) {
    v.x = fmaxf(v.x, 0.f);
    v.y = fmaxf(v.y, 0.f);
    v.z = fmaxf(v.z, 0.f);
    v.w = fmaxf(v.w, 0.f);
  }
  *(float4*)(Bout + (size_t)i * 128 + lane * 4) = v;

  if (pooled) {
    int g = batch[i];
    float* o = pooled + (size_t)g * 128 + lane * 4;
    atomicAdd(o + 0, v.x);
    atomicAdd(o + 1, v.y);
    atomicAdd(o + 2, v.z);
    atomicAdd(o + 3, v.w);
  }
}

// ---------------- head ----------------

__global__ __launch_bounds__(THREADS) void k_head(const float* __restrict__ pooled,
                                                  const float* __restrict__ cnts,
                                                  const float* __restrict__ Wl,
                                                  const float* __restrict__ bl,
                                                  float* __restrict__ out, int G) {
  int gid = blockIdx.x * THREADS + threadIdx.x;
  int g = gid >> 3;
  int o = gid & 7;
  if (g >= G) return;
  float acc = 0.f;
#pragma unroll 8
  for (int k = 0; k < 128; ++k) acc = fmaf(pooled[(size_t)g * 128 + k], Wl[k * 8 + o], acc);
  out[g * 8 + o] = acc / fmaxf(cnts[g], 1.0f) + bl[o];
}

// ---------------- launch ----------------

extern "C" void kernel_launch(void* const* d_in, const int* in_sizes, int n_in,
                              void* d_out, int out_size, void* d_ws, size_t ws_size,
                              hipStream_t stream) {
  const float* x     = (const float*)d_in[0];
  const int*   ei    = (const int*)d_in[1];
  const int*   batch = (const int*)d_in[3];
  const float* W1 = (const float*)d_in[4];
  const float* b1 = (const float*)d_in[5];
  const float* W2 = (const float*)d_in[6];
  const float* b2 = (const float*)d_in[7];
  const float* W3 = (const float*)d_in[8];
  const float* b3 = (const float*)d_in[9];
  const float* Wl = (const float*)d_in[10];
  const float* bl = (const float*)d_in[11];
  float* out = (float*)d_out;

  const int N = in_sizes[0] / 128;
  const int E = in_sizes[1] / 2;
  const int G = out_size / 8;
  const int* srcp = ei;
  const int* dstp = ei + E;

  char* ws = (char*)d_ws;
  __half* H16 = (__half*)ws;                       // [N,128] fp16 GEMM output
  float*  B   = (float*)(H16 + (size_t)N * 128);   // [N,128] fp32 agg/activation
  // zeroed region: degi, cursor, cnts, pooled (contiguous)
  int*   degi   = (int*)(B + (size_t)N * 128);     // N
  int*   cursor = degi + N;                        // N
  float* cnts   = (float*)(cursor + N);            // G
  float* pooled = cnts + G;                        // G*128
  // non-zeroed scratch
  float* dinv    = pooled + (size_t)G * 128;       // N
  int*   rowptr  = (int*)(dinv + N);               // N+1
  int*   bsum    = rowptr + N + 1;                 // scan partials (<=2048)
  int*   csr_src = bsum + 2048;                    // E
  float* csr_w   = (float*)(csr_src + E);          // E

  const size_t zero_bytes = ((size_t)2 * N + G + (size_t)G * 128) * sizeof(float);
  hipMemsetAsync(degi, 0, zero_bytes, stream);

  const int nbE = (E + THREADS - 1) / THREADS;
  const int nbN = (N + THREADS - 1) / THREADS;

  // ---- CSR build (once per call, reused by all 3 layers) ----
  k_deg<<<nbE, THREADS, 0, stream>>>(dstp, degi, E);
  k_cnt<<<nbN, THREADS, 0, stream>>>(batch, cnts, N);
  k_rsq<<<nbN, THREADS, 0, stream>>>(degi, dinv, N);
  k_scan1<<<nbN, THREADS, 0, stream>>>(degi, rowptr, bsum, N);
  k_scan2<<<1, 512, 0, stream>>>(bsum, nbN);
  k_scan3<<<nbN, THREADS, 0, stream>>>(rowptr, bsum, N, E);
  k_csr<<<nbE, THREADS, 0, stream>>>(srcp, dstp, rowptr, cursor, dinv, csr_src, csr_w, E);

  const int gemm_blocks = (N + 63) / 64;
  const int gat_blocks = (int)(((long long)N * 32 + THREADS - 1) / THREADS);

  // ---- layer 1 ----
  k_gemm128<<<gemm_blocks, THREADS, 0, stream>>>(x, W1, H16, N);
  k_gather<<<gat_blocks, THREADS, 0, stream>>>(H16, rowptr, csr_src, csr_w, dinv, b1, B, N, 1,
                                               nullptr, nullptr);
  // ---- layer 2 ----
  k_gemm128<<<gemm_blocks, THREADS, 0, stream>>>(B, W2, H16, N);
  k_gather<<<gat_blocks, THREADS, 0, stream>>>(H16, rowptr, csr_src, csr_w, dinv, b2, B, N, 1,
                                               nullptr, nullptr);
  // ---- layer 3 (no relu, fused mean-pool accumulation) ----
  k_gemm128<<<gemm_blocks, THREADS, 0, stream>>>(B, W3, H16, N);
  k_gather<<<gat_blocks, THREADS, 0, stream>>>(H16, rowptr, csr_src, csr_w, dinv, b3, B, N, 0,
                                               batch, pooled);

  // ---- head ----
  k_head<<<(G * 8 + THREADS - 1) / THREADS, THREADS, 0, stream>>>(pooled, cnts, Wl, bl, out, G);
}